// Round 1
// baseline (506.091 us; speedup 1.0000x reference)
//
#include <hip/hip_runtime.h>
#include <hip/hip_bf16.h>

#define NN 8192
#define DIN 128
#define DOUT 128

typedef __bf16 bf16;
typedef __bf16 bf16x4 __attribute__((ext_vector_type(4)));
typedef __bf16 bf16x8 __attribute__((ext_vector_type(8)));
typedef float f32x4 __attribute__((ext_vector_type(4)));

// ---------------- K1: row sums -> dinv[i] = rsqrt(sum(adj[i,:]) + eps) ----
__global__ __launch_bounds__(256) void k1_rowsum(const float* __restrict__ adj,
                                                 float* __restrict__ dinv) {
    int wave = threadIdx.x >> 6;
    int lane = threadIdx.x & 63;
    int row  = blockIdx.x * 4 + wave;
    const float4* p = reinterpret_cast<const float4*>(adj + (size_t)row * NN);
    float s = 0.f;
    #pragma unroll
    for (int i = 0; i < 32; ++i) {
        float4 v = p[lane + i * 64];           // 1 KiB/wave-inst, coalesced
        s += (v.x + v.y) + (v.z + v.w);
    }
    #pragma unroll
    for (int off = 32; off > 0; off >>= 1) s += __shfl_down(s, off, 64);
    if (lane == 0) dinv[row] = rsqrtf(s + 1e-6f);
}

// ---------------- K2: yT[c][j] = bf16(dinv[j] * x[j][c])  (transposed) ----
__global__ __launch_bounds__(256) void k2_transpose(const float* __restrict__ x,
                                                    const float* __restrict__ dinv,
                                                    bf16* __restrict__ yT) {
    __shared__ bf16 T[DIN][136];   // 136*2=272B row stride, 16B-aligned
    __shared__ float dl[128];
    int t  = threadIdx.x;
    int j0 = blockIdx.x * 128;
    if (t < 128) dl[t] = dinv[j0 + t];
    __syncthreads();
    #pragma unroll
    for (int s = 0; s < 16; ++s) {
        int i  = t + s * 256;
        int j  = i >> 5;          // 0..127
        int c4 = i & 31;          // 0..31
        float4 v = *reinterpret_cast<const float4*>(x + (size_t)(j0 + j) * DIN + c4 * 4);
        float d = dl[j];
        T[c4 * 4 + 0][j] = (bf16)(v.x * d);
        T[c4 * 4 + 1][j] = (bf16)(v.y * d);
        T[c4 * 4 + 2][j] = (bf16)(v.z * d);
        T[c4 * 4 + 3][j] = (bf16)(v.w * d);
    }
    __syncthreads();
    #pragma unroll
    for (int s = 0; s < 8; ++s) {
        int i  = t + s * 256;
        int c  = i >> 4;          // 0..127
        int j8 = i & 15;          // 16B chunks
        *reinterpret_cast<uint4*>(yT + (size_t)c * NN + j0 + j8 * 8) =
            *reinterpret_cast<const uint4*>(&T[c][j8 * 8]);
    }
}

// ---------------- K3: hp[split] = adj[rows, ksplit] @ y[ksplit, :] --------
// BM=32, BK=64, BN=128, split-K=2. 4 waves; wave wn owns cols wn*32..+31.
#define LDA 72   // bf16 elems; 144B row stride = 9*16B (b128-aligned)
#define LDB 72

__global__ __launch_bounds__(256) void k3_gemm(const float* __restrict__ adj,
                                               const bf16* __restrict__ yT,
                                               float* __restrict__ hp) {
    __shared__ bf16 Asm[32 * LDA];
    __shared__ bf16 Bsm[128 * LDB];
    int t     = threadIdx.x;
    int mb    = blockIdx.x >> 1;
    int split = blockIdx.x & 1;
    int m0    = mb * 32;
    int k0    = split * 4096;
    int lane  = t & 63;
    int wn    = t >> 6;            // 0..3
    int mrow  = lane & 15;
    int quad  = lane >> 4;

    f32x4 acc[2][2] = {};          // [mi][ni] 16x16 tiles

    const float* aptr = adj + (size_t)m0 * NN + k0;
    const bf16*  bptr = yT + k0;

    for (int kk = 0; kk < 64; ++kk) {
        int col0 = kk * 64;
        __syncthreads();
        // stage A: 32 rows x 64 fp32 -> bf16 LDS (2 float4 per thread)
        #pragma unroll
        for (int s = 0; s < 2; ++s) {
            int i   = t + s * 256;
            int row = i >> 4;
            int c4  = i & 15;
            float4 v = *reinterpret_cast<const float4*>(aptr + (size_t)row * NN + col0 + c4 * 4);
            bf16x4 bv = { (bf16)v.x, (bf16)v.y, (bf16)v.z, (bf16)v.w };
            *reinterpret_cast<bf16x4*>(&Asm[row * LDA + c4 * 4]) = bv;
        }
        // stage B: 128 n-rows x 64 k bf16 (4 x 16B per thread)
        #pragma unroll
        for (int s = 0; s < 4; ++s) {
            int i  = t + s * 256;
            int n  = i >> 3;
            int c8 = i & 7;
            uint4 v = *reinterpret_cast<const uint4*>(bptr + (size_t)n * NN + col0 + c8 * 8);
            *reinterpret_cast<uint4*>(&Bsm[n * LDB + c8 * 8]) = v;
        }
        __syncthreads();
        // compute: 2 k-substeps of 32, 2x2 MFMA tiles per wave
        #pragma unroll
        for (int ks = 0; ks < 2; ++ks) {
            bf16x8 af[2], bfr[2];
            #pragma unroll
            for (int mi = 0; mi < 2; ++mi)
                af[mi] = *reinterpret_cast<const bf16x8*>(
                    &Asm[(mi * 16 + mrow) * LDA + ks * 32 + quad * 8]);
            #pragma unroll
            for (int ni = 0; ni < 2; ++ni)
                bfr[ni] = *reinterpret_cast<const bf16x8*>(
                    &Bsm[(wn * 32 + ni * 16 + mrow) * LDB + ks * 32 + quad * 8]);
            #pragma unroll
            for (int mi = 0; mi < 2; ++mi)
                #pragma unroll
                for (int ni = 0; ni < 2; ++ni)
                    acc[mi][ni] = __builtin_amdgcn_mfma_f32_16x16x32_bf16(
                        af[mi], bfr[ni], acc[mi][ni], 0, 0, 0);
        }
    }
    // epilogue: D[row=quad*4+reg][col=lane&15]
    float* out = hp + (size_t)split * (NN * DIN);
    #pragma unroll
    for (int mi = 0; mi < 2; ++mi)
        #pragma unroll
        for (int ni = 0; ni < 2; ++ni) {
            int col = wn * 32 + ni * 16 + mrow;
            #pragma unroll
            for (int r = 0; r < 4; ++r) {
                int row = m0 + mi * 16 + quad * 4 + r;
                out[(size_t)row * DIN + col] = acc[mi][ni][r];
            }
        }
}

// ---------------- K4: out = (hp0+hp1)*dinv[i] @ W^T + b  (fp32) -----------
__global__ __launch_bounds__(256) void k4_out(const float* __restrict__ hp,
                                              const float* __restrict__ dinv,
                                              const float* __restrict__ W,
                                              const float* __restrict__ bias,
                                              float* __restrict__ out) {
    __shared__ float Wl[128 * 132];   // pad to 132: uniform bank spread for b128
    __shared__ float hl[32 * 132];
    __shared__ float bl[128];
    int t  = threadIdx.x;
    int i0 = blockIdx.x * 32;
    if (t < 128) bl[t] = bias[t];
    #pragma unroll
    for (int s = 0; s < 16; ++s) {
        int i  = t + s * 256;
        int o  = i >> 5;
        int c4 = i & 31;
        *reinterpret_cast<float4*>(&Wl[o * 132 + c4 * 4]) =
            *reinterpret_cast<const float4*>(W + o * 128 + c4 * 4);
    }
    const float* hp0 = hp;
    const float* hp1 = hp + (size_t)NN * DIN;
    #pragma unroll
    for (int s = 0; s < 4; ++s) {
        int i   = t + s * 256;
        int row = i >> 5;
        int c4  = i & 31;
        size_t g = (size_t)(i0 + row) * DIN + c4 * 4;
        float4 v0 = *reinterpret_cast<const float4*>(hp0 + g);
        float4 v1 = *reinterpret_cast<const float4*>(hp1 + g);
        float d = dinv[i0 + row];
        float4 hv = { (v0.x + v1.x) * d, (v0.y + v1.y) * d,
                      (v0.z + v1.z) * d, (v0.w + v1.w) * d };
        *reinterpret_cast<float4*>(&hl[row * 132 + c4 * 4]) = hv;
    }
    __syncthreads();
    int o = t & 127;
    int g = t >> 7;                 // rows g*16 .. g*16+15
    float acc[16];
    #pragma unroll
    for (int r = 0; r < 16; ++r) acc[r] = bl[o];
    for (int c4 = 0; c4 < 32; ++c4) {
        float4 w4 = *reinterpret_cast<const float4*>(&Wl[o * 132 + c4 * 4]);
        #pragma unroll
        for (int r = 0; r < 16; ++r) {
            float4 h4 = *reinterpret_cast<const float4*>(&hl[(g * 16 + r) * 132 + c4 * 4]);
            acc[r] += h4.x * w4.x + h4.y * w4.y + h4.z * w4.z + h4.w * w4.w;
        }
    }
    #pragma unroll
    for (int r = 0; r < 16; ++r)
        out[(size_t)(i0 + g * 16 + r) * DOUT + o] = acc[r];
}

extern "C" void kernel_launch(void* const* d_in, const int* in_sizes, int n_in,
                              void* d_out, int out_size, void* d_ws, size_t ws_size,
                              hipStream_t stream) {
    const float* x   = (const float*)d_in[0];
    const float* adj = (const float*)d_in[1];
    const float* W   = (const float*)d_in[2];
    const float* b   = (const float*)d_in[3];
    float* out = (float*)d_out;
    char* ws = (char*)d_ws;
    float* dinv = (float*)ws;                  // 32 KB
    bf16*  yT   = (bf16*)(ws + (1 << 20));     // 2 MB @ 1MB
    float* hp   = (float*)(ws + (3 << 20));    // 2 x 4 MB @ 3MB

    k1_rowsum  <<<NN / 4, 256, 0, stream>>>(adj, dinv);
    k2_transpose<<<NN / 128, 256, 0, stream>>>(x, dinv, yT);
    k3_gemm    <<<(NN / 32) * 2, 256, 0, stream>>>(adj, yT, hp);
    k4_out     <<<NN / 32, 256, 0, stream>>>(hp, dinv, W, b, out);
}